// Round 1
// baseline (459.242 us; speedup 1.0000x reference)
//
#include <hip/hip_runtime.h>

#define BATCH 2048

// block-wide f32 sum; all threads get the result. red >= 32 floats.
__device__ __forceinline__ float blockReduceSumF(float v, float* red, int tid, int nwaves) {
  #pragma unroll
  for (int off = 32; off > 0; off >>= 1) v += __shfl_xor(v, off);
  __syncthreads();
  if ((tid & 63) == 0) red[tid >> 6] = v;
  __syncthreads();
  if (tid == 0) {
    float s = red[0];
    for (int i = 1; i < nwaves; i++) s += red[i];
    red[31] = s;
  }
  __syncthreads();
  return red[31];
}

// packed 2-value block reduce (one barrier sequence); per-component order identical
// to two sequential blockReduceSumF calls -> bit-exact. red >= 32 floats; nwaves <= 8.
__device__ __forceinline__ float2 blockReduceSum2F(float a, float b, float* red, int tid, int nwaves) {
  #pragma unroll
  for (int off = 32; off > 0; off >>= 1) { a += __shfl_xor(a, off); b += __shfl_xor(b, off); }
  __syncthreads();
  if ((tid & 63) == 0) { red[tid >> 6] = a; red[(tid >> 6) + 16] = b; }
  __syncthreads();
  if (tid == 0) {
    float sa = red[0], sb = red[16];
    for (int i = 1; i < nwaves; i++) { sa += red[i]; sb += red[16 + i]; }
    red[30] = sa; red[31] = sb;
  }
  __syncthreads();
  return make_float2(red[30], red[31]);
}

// 4-wave (256-thread) group reduce; seg = 4-float LDS segment for this group.
__device__ __forceinline__ float groupReduce4w(float v, float* seg, int tj) {
  #pragma unroll
  for (int off = 32; off > 0; off >>= 1) v += __shfl_xor(v, off);
  __syncthreads();
  if ((tj & 63) == 0) seg[tj >> 6] = v;
  __syncthreads();
  return (seg[0] + seg[1]) + (seg[2] + seg[3]);
}

// ---------------- K0a: pack conv2 weights -> w2t2[cc][c2][28] (229 KB) ----------------
// k<25: w2t2[(cc*64+c2)*28+k] = w2[c2*800 + cc*25 + k]; k in 25..27 zero-padded so each
// thread's 25 weights are 7 aligned float4 loads (112 B, 16B-aligned for every c2).
__global__ void k0_w2t(const float* __restrict__ w2, float* __restrict__ w2t2) {
  int i = blockIdx.x * 256 + threadIdx.x;  // over 57344
  if (i >= 57344) return;
  int cc = i / 1792;
  int r = i - cc * 1792;
  int c2 = r / 28;
  int k = r - c2 * 28;
  w2t2[i] = (k < 25) ? w2[c2 * 800 + cc * 25 + k] : 0.0f;
}

// ---------------- K1: conv1 + ternarize -> sign map + alpha1 (f32) ----------------
__global__ __launch_bounds__(512, 6) void k1_conv1(
    const float* __restrict__ x, const float* __restrict__ w1, const float* __restrict__ b1,
    signed char* __restrict__ s1full, float* __restrict__ alpha1) {
  __shared__ float xs[784];
  __shared__ float wsm[800];
  __shared__ float red[32];

  const int tid = threadIdx.x;
  const int smp = blockIdx.x;

  for (int j = tid; j < 784; j += 512) xs[j] = x[smp * 784 + j];
  for (int j = tid; j < 800; j += 512) wsm[j] = w1[j];
  __syncthreads();

  const int c = tid >> 4;
  const int g = tid & 15;
  const float bias = b1[c];
  const float* wc = &wsm[c * 25];

  float a[36];
  float asum = 0.0f;
  #pragma unroll
  for (int tt = 0; tt < 3; tt++) {
    const int t = g + (tt << 4);
    const int r = t >> 1;
    const int hx = (t & 1) * 12;
    float acc[12];
    #pragma unroll
    for (int i = 0; i < 12; i++) acc[i] = bias;
    #pragma unroll
    for (int ky = 0; ky < 5; ky++) {
      const float* xp = &xs[(r + ky) * 28 + hx];
      float xrow[16];
      *(float4*)&xrow[0]  = *(const float4*)&xp[0];
      *(float4*)&xrow[4]  = *(const float4*)&xp[4];
      *(float4*)&xrow[8]  = *(const float4*)&xp[8];
      *(float4*)&xrow[12] = *(const float4*)&xp[12];
      #pragma unroll
      for (int kx = 0; kx < 5; kx++) {
        const float w = wc[ky * 5 + kx];
        #pragma unroll
        for (int i = 0; i < 12; i++) acc[i] = fmaf(xrow[i + kx], w, acc[i]);
      }
    }
    #pragma unroll
    for (int i = 0; i < 12; i++) { a[tt * 12 + i] = acc[i]; asum += fabsf(acc[i]); }
  }

  float tot = blockReduceSumF(asum, red, tid, 8);
  float delta = (0.7f * tot) / 18432.0f;

  float msum = 0.0f, mcnt = 0.0f;
  #pragma unroll
  for (int i = 0; i < 36; i++) {
    float fa = fabsf(a[i]);
    if (fa > delta) { msum += fa; mcnt += 1.0f; }
  }
  float2 mm = blockReduceSum2F(msum, mcnt, red, tid, 8);
  if (tid == 0) alpha1[smp] = (mm.y > 0.0f) ? (mm.x / mm.y) : 0.0f;

  // R15: pack 12 sign bytes -> 3 dword stores (was 12 byte stores per tt).
  signed char* sp = s1full + (size_t)smp * 18432 + c * 576 + g * 12;
  #pragma unroll
  for (int tt = 0; tt < 3; tt++) {
    int s_[12];
    #pragma unroll
    for (int i = 0; i < 12; i++) {
      float v = a[tt * 12 + i];
      s_[i] = (v > delta) ? 1 : ((v < -delta) ? -1 : 0);
    }
    unsigned u0 = (s_[0] & 0xFF) | ((s_[1] & 0xFF) << 8) | ((s_[2] & 0xFF) << 16) |
                  (((unsigned)(s_[3] & 0xFF)) << 24);
    unsigned u1 = (s_[4] & 0xFF) | ((s_[5] & 0xFF) << 8) | ((s_[6] & 0xFF) << 16) |
                  (((unsigned)(s_[7] & 0xFF)) << 24);
    unsigned u2 = (s_[8] & 0xFF) | ((s_[9] & 0xFF) << 8) | ((s_[10] & 0xFF) << 16) |
                  (((unsigned)(s_[11] & 0xFF)) << 24);
    unsigned* wq = (unsigned*)(sp + tt * 192);
    wq[0] = u0; wq[1] = u1; wq[2] = u2;
  }
}

// ---------------- K2: BN1+maxpool+relu, conv2, ternarize ----
// R15: (a) weights repacked w2t2[cc][c2][28] -> 7 float4 loads per cc (was 25 scalar
// gathers); (b) software double-buffer: cc+1 weights loaded into named A/B float4 regs
// during cc's 400 FMAs so L2 latency hides under compute; launch_bounds (256,4) gives
// the allocator headroom (~110 VGPR) instead of the 40-VGPR/batched-vmcnt schedule.
// FMA order/operands bitwise-identical to R14.
__device__ __forceinline__ void conv_body(const float* __restrict__ pb, int r0,
    float4 W0, float4 W1, float4 W2, float4 W3, float4 W4, float4 W5, float4 W6,
    float* __restrict__ acc0, float* __restrict__ acc1) {
  const float wk[25] = {W0.x, W0.y, W0.z, W0.w, W1.x, W1.y, W1.z, W1.w,
                        W2.x, W2.y, W2.z, W2.w, W3.x, W3.y, W3.z, W3.w,
                        W4.x, W4.y, W4.z, W4.w, W5.x, W5.y, W5.z, W5.w, W6.x};
  float rows[2][12];
  *(float4*)&rows[0][0] = *(const float4*)&pb[r0 * 12];
  *(float4*)&rows[0][4] = *(const float4*)&pb[r0 * 12 + 4];
  *(float4*)&rows[0][8] = *(const float4*)&pb[r0 * 12 + 8];
  #pragma unroll
  for (int ky = 0; ky < 5; ky++) {
    float* B = rows[(ky + 1) & 1];
    const float* bp = &pb[(r0 + ky + 1) * 12];
    *(float4*)&B[0] = *(const float4*)&bp[0];
    *(float4*)&B[4] = *(const float4*)&bp[4];
    *(float4*)&B[8] = *(const float4*)&bp[8];
    const float* A = rows[ky & 1];
    #pragma unroll
    for (int kx = 0; kx < 5; kx++) {
      const float w = wk[ky * 5 + kx];
      #pragma unroll
      for (int ox = 0; ox < 8; ox++) acc0[ox] = fmaf(A[ox + kx], w, acc0[ox]);
      #pragma unroll
      for (int ox = 0; ox < 8; ox++) acc1[ox] = fmaf(B[ox + kx], w, acc1[ox]);
    }
  }
}

__global__ __launch_bounds__(256, 4) void k2_conv2(
    const signed char* __restrict__ s1full, const float* __restrict__ alpha1,
    const float* __restrict__ w2t2, const float* __restrict__ b2,
    const float* __restrict__ g1, const float* __restrict__ bt1,
    signed char* __restrict__ s2full, float* __restrict__ alpha2) {
  __shared__ float pooled[4608];
  __shared__ float g1l[32], bt1l[32];
  __shared__ float red[32];

  const int tid = threadIdx.x;
  const int smp = blockIdx.x;
  const float BNINV = (float)(1.0 / sqrt(1.0 + 1e-5));

  if (tid < 32) { g1l[tid] = g1[tid] * BNINV; bt1l[tid] = bt1[tid]; }
  __syncthreads();

  const float a1 = alpha1[smp];
  for (int j = tid; j < 4608; j += 256) {
    int ci = j / 144;
    int r = j - ci * 144;
    int py = r / 12;
    int px = r - py * 12;
    const signed char* sp = s1full + (size_t)smp * 18432 + ci * 576 + (py * 2) * 24 + px * 2;
    char2 t0 = *(const char2*)sp;
    char2 t1 = *(const char2*)(sp + 24);
    float m = -1e30f;
    { float v = ((float)t0.x * a1) * g1l[ci] + bt1l[ci]; m = (v > m) ? v : m; }
    { float v = ((float)t0.y * a1) * g1l[ci] + bt1l[ci]; m = (v > m) ? v : m; }
    { float v = ((float)t1.x * a1) * g1l[ci] + bt1l[ci]; m = (v > m) ? v : m; }
    { float v = ((float)t1.y * a1) * g1l[ci] + bt1l[ci]; m = (v > m) ? v : m; }
    pooled[j] = (m > 0.0f) ? m : 0.0f;
  }
  __syncthreads();

  const int c2 = tid >> 2;
  const int q = tid & 3;
  const int r0 = q << 1;
  const float bias = b2[c2];
  float acc0[8], acc1[8];
  #pragma unroll
  for (int i = 0; i < 8; i++) { acc0[i] = bias; acc1[i] = bias; }

  const float4* wbase = ((const float4*)w2t2) + c2 * 7;  // 112 B/c2 -> 16B-aligned
  const float4* wp = wbase;
  float4 A0 = wp[0], A1 = wp[1], A2 = wp[2], A3 = wp[3], A4 = wp[4], A5 = wp[5], A6 = wp[6];
  #pragma unroll 1
  for (int cc = 0; cc < 32; cc += 2) {
    const float4* wn = wp + 448;  // cc+1 slab (448 float4 = 64 c2 * 7)
    float4 B0 = wn[0], B1 = wn[1], B2 = wn[2], B3 = wn[3], B4 = wn[4], B5 = wn[5], B6 = wn[6];
    conv_body(&pooled[cc * 144], r0, A0, A1, A2, A3, A4, A5, A6, acc0, acc1);
    const float4* wn2 = (cc < 30) ? (wp + 896) : wbase;  // cc+2 (dummy reload at tail)
    A0 = wn2[0]; A1 = wn2[1]; A2 = wn2[2]; A3 = wn2[3]; A4 = wn2[4]; A5 = wn2[5]; A6 = wn2[6];
    conv_body(&pooled[(cc + 1) * 144], r0, B0, B1, B2, B3, B4, B5, B6, acc0, acc1);
    wp += 896;
  }

  float asum = 0.0f;
  #pragma unroll
  for (int i = 0; i < 8; i++) asum += fabsf(acc0[i]) + fabsf(acc1[i]);
  float tot = blockReduceSumF(asum, red, tid, 4);
  float delta = (0.7f * tot) / 4096.0f;

  float msum = 0.0f, mcnt = 0.0f;
  #pragma unroll
  for (int i = 0; i < 8; i++) {
    float f0 = fabsf(acc0[i]);
    if (f0 > delta) { msum += f0; mcnt += 1.0f; }
    float f1 = fabsf(acc1[i]);
    if (f1 > delta) { msum += f1; mcnt += 1.0f; }
  }
  float2 mm = blockReduceSum2F(msum, mcnt, red, tid, 4);
  if (tid == 0) alpha2[smp] = (mm.y > 0.0f) ? (mm.x / mm.y) : 0.0f;

  // R15: pack 16 sign bytes -> one uint4 store (16B-aligned: r0 even).
  int t_[16];
  #pragma unroll
  for (int ox = 0; ox < 8; ox++) {
    float v = acc0[ox];
    t_[ox] = (v > delta) ? 1 : ((v < -delta) ? -1 : 0);
  }
  #pragma unroll
  for (int ox = 0; ox < 8; ox++) {
    float v = acc1[ox];
    t_[8 + ox] = (v > delta) ? 1 : ((v < -delta) ? -1 : 0);
  }
  unsigned u0 = (t_[0] & 0xFF) | ((t_[1] & 0xFF) << 8) | ((t_[2] & 0xFF) << 16) |
                (((unsigned)(t_[3] & 0xFF)) << 24);
  unsigned u1 = (t_[4] & 0xFF) | ((t_[5] & 0xFF) << 8) | ((t_[6] & 0xFF) << 16) |
                (((unsigned)(t_[7] & 0xFF)) << 24);
  unsigned u2 = (t_[8] & 0xFF) | ((t_[9] & 0xFF) << 8) | ((t_[10] & 0xFF) << 16) |
                (((unsigned)(t_[11] & 0xFF)) << 24);
  unsigned u3 = (t_[12] & 0xFF) | ((t_[13] & 0xFF) << 8) | ((t_[14] & 0xFF) << 16) |
                (((unsigned)(t_[15] & 0xFF)) << 24);
  *(uint4*)(s2full + (size_t)smp * 4096 + c2 * 64 + r0 * 8) = make_uint4(u0, u1, u2, u3);
}

// ---------------- K0t: transpose fc1 weights into w1t[k][o] (into dead s1full) ----------
__global__ void k0_transpose(const float* __restrict__ w1f, float* __restrict__ w1t) {
  int i = blockIdx.x * 256 + threadIdx.x;  // i over 524288
  int k = i >> 9;
  int o = i & 511;
  w1t[i] = w1f[o * 1024 + k];
}

// ---------------- K3: 4 samples/block; fc1 via transposed weights — R13 verbatim ----
__global__ __launch_bounds__(1024, 4) void k3_fc(
    const signed char* __restrict__ s2full, const float* __restrict__ alpha2,
    const float* __restrict__ w1t, const float* __restrict__ f1b,
    const float* __restrict__ w2f, const float* __restrict__ f2b,
    const float* __restrict__ g2, const float* __restrict__ bt2,
    float* __restrict__ out) {
  __shared__ float S[16384];
  __shared__ float fco[4][512];
  __shared__ float g2l[64], bt2l[64];
  __shared__ float redm[4][4];
  __shared__ float out2[4][10];

  const int tid = threadIdx.x;
  const int blk = blockIdx.x;
  const float BNINV = (float)(1.0 / sqrt(1.0 + 1e-5));

  if (tid < 64) { g2l[tid] = g2[tid] * BNINV; bt2l[tid] = bt2[tid]; }
  __syncthreads();

  float* h4 = S;
  for (int e = tid; e < 4096; e += 1024) {
    int j = e >> 2;
    int s = e & 3;
    int cc = j >> 4;
    int r = j & 15;
    int py = r >> 2;
    int px = r & 3;
    const signed char* sp = s2full + (size_t)(blk * 4 + s) * 4096 + cc * 64 + (py * 2) * 8 + px * 2;
    float a2 = alpha2[blk * 4 + s];
    float m = -1e30f;
    #pragma unroll
    for (int dy = 0; dy < 2; dy++)
      #pragma unroll
      for (int dx = 0; dx < 2; dx++) {
        float v = ((float)sp[dy * 8 + dx] * a2) * g2l[cc] + bt2l[cc];
        m = (v > m) ? v : m;
      }
    h4[j * 4 + s] = (m > 0.0f) ? m : 0.0f;
  }
  __syncthreads();

  const int kp = tid >> 7;
  const int og = tid & 127;
  float a00=0,a01=0,a02=0,a03=0, a10=0,a11=0,a12=0,a13=0;
  float a20=0,a21=0,a22=0,a23=0, a30=0,a31=0,a32=0,a33=0;
  const float4* w4 = (const float4*)w1t;
  const float4* h44 = (const float4*)h4;
  const int kbase = kp << 7;
  for (int kk = 0; kk < 128; kk++) {
    const int k = kbase + kk;
    const float4 wv = w4[(k << 7) + og];
    const float4 hv = h44[k];
    a00 = fmaf(hv.x, wv.x, a00); a01 = fmaf(hv.y, wv.x, a01);
    a02 = fmaf(hv.z, wv.x, a02); a03 = fmaf(hv.w, wv.x, a03);
    a10 = fmaf(hv.x, wv.y, a10); a11 = fmaf(hv.y, wv.y, a11);
    a12 = fmaf(hv.z, wv.y, a12); a13 = fmaf(hv.w, wv.y, a13);
    a20 = fmaf(hv.x, wv.z, a20); a21 = fmaf(hv.y, wv.z, a21);
    a22 = fmaf(hv.z, wv.z, a22); a23 = fmaf(hv.w, wv.z, a23);
    a30 = fmaf(hv.x, wv.w, a30); a31 = fmaf(hv.y, wv.w, a31);
    a32 = fmaf(hv.z, wv.w, a32); a33 = fmaf(hv.w, wv.w, a33);
  }
  __syncthreads();
  {
    float4* p4 = (float4*)S;
    const int base = (kp << 9) + (og << 2);
    p4[base + 0] = make_float4(a00, a01, a02, a03);
    p4[base + 1] = make_float4(a10, a11, a12, a13);
    p4[base + 2] = make_float4(a20, a21, a22, a23);
    p4[base + 3] = make_float4(a30, a31, a32, a33);
  }
  __syncthreads();

  for (int p = tid; p < 2048; p += 1024) {
    int o = p >> 2;
    int s = p & 3;
    float v = S[p];
    #pragma unroll
    for (int kp2 = 1; kp2 < 8; kp2++) v += S[kp2 * 2048 + p];
    fco[s][o] = v + f1b[o];
  }
  __syncthreads();

  float (*h3)[512] = (float(*)[512])S;
  const int sg = tid >> 8;
  const int tj = tid & 255;
  float v0 = fco[sg][tj];
  float v1 = fco[sg][tj + 256];
  float av0 = fabsf(v0), av1 = fabsf(v1);
  float tot = groupReduce4w(av0 + av1, redm[sg], tj);
  float delta = (0.7f * tot) / 512.0f;
  float m0 = (av0 > delta) ? av0 : 0.0f;
  float m1 = (av1 > delta) ? av1 : 0.0f;
  float msum = groupReduce4w(m0 + m1, redm[sg], tj);
  float mcnt = groupReduce4w(((av0 > delta) ? 1.0f : 0.0f) + ((av1 > delta) ? 1.0f : 0.0f),
                             redm[sg], tj);
  float alpha3 = (mcnt > 0.0f) ? (msum / mcnt) : 0.0f;
  {
    float t0 = (v0 > delta) ? 1.0f : ((v0 < -delta) ? -1.0f : 0.0f);
    float hv0 = t0 * alpha3;
    h3[sg][tj] = (hv0 > 0.0f) ? hv0 : 0.0f;
    float t1 = (v1 > delta) ? 1.0f : ((v1 < -delta) ? -1.0f : 0.0f);
    float hv1 = t1 * alpha3;
    h3[sg][tj + 256] = (hv1 > 0.0f) ? hv1 : 0.0f;
  }
  __syncthreads();

  const int lane = tid & 63;
  const int wid = tid >> 6;
  for (int t = wid; t < 40; t += 16) {
    int s = t / 10;
    int o = t - s * 10;
    float acc = 0.0f;
    #pragma unroll
    for (int m = 0; m < 8; m++) {
      int j = lane + (m << 6);
      acc = fmaf(h3[s][j], w2f[o * 512 + j], acc);
    }
    #pragma unroll
    for (int off = 32; off > 0; off >>= 1) acc += __shfl_xor(acc, off);
    if (lane == 0) out2[s][o] = acc + f2b[o];
  }
  __syncthreads();

  if (tid < 4) {
    int s = tid;
    float t2 = 0.0f;
    for (int i = 0; i < 10; i++) t2 += fabsf(out2[s][i]);
    float d = (0.7f * t2) / 10.0f;
    float ms = 0.0f, mc = 0.0f;
    for (int i = 0; i < 10; i++) {
      float a = fabsf(out2[s][i]);
      if (a > d) { ms += a; mc += 1.0f; }
    }
    float al = (mc > 0.0f) ? (ms / mc) : 0.0f;
    for (int i = 0; i < 10; i++) {
      float vv = out2[s][i];
      float sv = (vv > d) ? 1.0f : ((vv < -d) ? -1.0f : 0.0f);
      out[(size_t)(blk * 4 + s) * 10 + i] = sv * al;
    }
  }
}

// assumption-violation marker
__global__ void k_marker(float* __restrict__ out, int n, float val) {
  int i = blockIdx.x * 256 + threadIdx.x;
  if (i < n) out[i] = val;
}

extern "C" void kernel_launch(void* const* d_in, const int* in_sizes, int n_in,
                              void* d_out, int out_size, void* d_ws, size_t ws_size,
                              hipStream_t stream) {
  float* out = (float*)d_out;

  static const int expect[13] = {1605632, 800, 32, 32, 32, 51200, 64, 64, 64,
                                 524288, 512, 5120, 10};
  float marker = 0.0f;
  if (n_in != 13) marker = 304.0f;
  else {
    for (int i = 0; i < 13; i++)
      if (in_sizes[i] != expect[i]) { marker = 320.0f + 16.0f * i; break; }
  }
  if (marker == 0.0f && out_size != 20480) marker = 560.0f;

  float* alpha1 = (float*)d_ws;                           // 2048
  float* alpha2 = alpha1 + BATCH;                         // 2048
  float* w2t2   = alpha2 + BATCH;                         // 57344 (229 KB, padded)
  signed char* s1full = (signed char*)(w2t2 + 57344);     // 2048*18432 (dead after k2;
                                                          //  first 2MB reused as w1t)
  signed char* s2full = s1full + (size_t)BATCH * 18432;   // 2048*4096
  size_t needed = (size_t)((s2full + (size_t)BATCH * 4096) - (signed char*)d_ws);
  if (marker == 0.0f && ws_size < needed) marker = 576.0f;

  if (marker != 0.0f) {
    k_marker<<<dim3((out_size + 255) / 256), dim3(256), 0, stream>>>(out, out_size, marker);
    return;
  }

  const float* x   = (const float*)d_in[0];
  const float* c1w = (const float*)d_in[1];
  const float* c1b = (const float*)d_in[2];
  const float* g1  = (const float*)d_in[3];
  const float* bt1 = (const float*)d_in[4];
  const float* c2w = (const float*)d_in[5];
  const float* c2b = (const float*)d_in[6];
  const float* g2  = (const float*)d_in[7];
  const float* bt2 = (const float*)d_in[8];
  const float* f1w = (const float*)d_in[9];
  const float* f1b = (const float*)d_in[10];
  const float* f2w = (const float*)d_in[11];
  const float* f2b = (const float*)d_in[12];

  float* w1t = (float*)s1full;

  k0_w2t<<<dim3(224), dim3(256), 0, stream>>>(c2w, w2t2);
  k1_conv1<<<dim3(BATCH), dim3(512), 0, stream>>>(x, c1w, c1b, s1full, alpha1);
  k2_conv2<<<dim3(BATCH), dim3(256), 0, stream>>>(s1full, alpha1, w2t2, c2b, g1, bt1, s2full, alpha2);
  k0_transpose<<<dim3(2048), dim3(256), 0, stream>>>(f1w, w1t);
  k3_fc<<<dim3(BATCH / 4), dim3(1024), 0, stream>>>(s2full, alpha2, w1t, f1b, f2w, f2b, g2, bt2, out);
}

// Round 2
// 348.925 us; speedup vs baseline: 1.3162x; 1.3162x over previous
//
#include <hip/hip_runtime.h>

#define BATCH 2048

// block-wide f32 sum; all threads get the result. red >= 32 floats.
__device__ __forceinline__ float blockReduceSumF(float v, float* red, int tid, int nwaves) {
  #pragma unroll
  for (int off = 32; off > 0; off >>= 1) v += __shfl_xor(v, off);
  __syncthreads();
  if ((tid & 63) == 0) red[tid >> 6] = v;
  __syncthreads();
  if (tid == 0) {
    float s = red[0];
    for (int i = 1; i < nwaves; i++) s += red[i];
    red[31] = s;
  }
  __syncthreads();
  return red[31];
}

// packed 2-value block reduce (one barrier sequence); per-component order identical
// to two sequential blockReduceSumF calls -> bit-exact. red >= 32 floats; nwaves <= 8.
__device__ __forceinline__ float2 blockReduceSum2F(float a, float b, float* red, int tid, int nwaves) {
  #pragma unroll
  for (int off = 32; off > 0; off >>= 1) { a += __shfl_xor(a, off); b += __shfl_xor(b, off); }
  __syncthreads();
  if ((tid & 63) == 0) { red[tid >> 6] = a; red[(tid >> 6) + 16] = b; }
  __syncthreads();
  if (tid == 0) {
    float sa = red[0], sb = red[16];
    for (int i = 1; i < nwaves; i++) { sa += red[i]; sb += red[16 + i]; }
    red[30] = sa; red[31] = sb;
  }
  __syncthreads();
  return make_float2(red[30], red[31]);
}

// 4-wave (256-thread) group reduce; seg = 4-float LDS segment for this group.
__device__ __forceinline__ float groupReduce4w(float v, float* seg, int tj) {
  #pragma unroll
  for (int off = 32; off > 0; off >>= 1) v += __shfl_xor(v, off);
  __syncthreads();
  if ((tj & 63) == 0) seg[tj >> 6] = v;
  __syncthreads();
  return (seg[0] + seg[1]) + (seg[2] + seg[3]);
}

// ---------------- K0a: pack conv2 weights -> w2t2[cc][c2][28] (229 KB) ----------------
__global__ void k0_w2t(const float* __restrict__ w2, float* __restrict__ w2t2) {
  int i = blockIdx.x * 256 + threadIdx.x;  // over 57344
  if (i >= 57344) return;
  int cc = i / 1792;
  int r = i - cc * 1792;
  int c2 = r / 28;
  int k = r - c2 * 28;
  w2t2[i] = (k < 25) ? w2[c2 * 800 + cc * 25 + k] : 0.0f;
}

// ---------------- K1: conv1 + ternarize -> sign map + alpha1 (f32) ----------------
// R16: launch_bounds (512,6)->(512,4). (512,6) capped VGPR at 40 while ~90 floats are
// live (a[36]+xrow[16]+acc[12]+temps) -> a[36] spilled to scratch: FETCH 250MB /
// WRITE 447MB / VALUBusy 0.7% observed. (512,4) = VGPR cap 128, 2 blocks/CU.
__global__ __launch_bounds__(512, 4) void k1_conv1(
    const float* __restrict__ x, const float* __restrict__ w1, const float* __restrict__ b1,
    signed char* __restrict__ s1full, float* __restrict__ alpha1) {
  __shared__ float xs[784];
  __shared__ float wsm[800];
  __shared__ float red[32];

  const int tid = threadIdx.x;
  const int smp = blockIdx.x;

  for (int j = tid; j < 784; j += 512) xs[j] = x[smp * 784 + j];
  for (int j = tid; j < 800; j += 512) wsm[j] = w1[j];
  __syncthreads();

  const int c = tid >> 4;
  const int g = tid & 15;
  const float bias = b1[c];
  const float* wc = &wsm[c * 25];

  float a[36];
  float asum = 0.0f;
  #pragma unroll
  for (int tt = 0; tt < 3; tt++) {
    const int t = g + (tt << 4);
    const int r = t >> 1;
    const int hx = (t & 1) * 12;
    float acc[12];
    #pragma unroll
    for (int i = 0; i < 12; i++) acc[i] = bias;
    #pragma unroll
    for (int ky = 0; ky < 5; ky++) {
      const float* xp = &xs[(r + ky) * 28 + hx];
      float xrow[16];
      *(float4*)&xrow[0]  = *(const float4*)&xp[0];
      *(float4*)&xrow[4]  = *(const float4*)&xp[4];
      *(float4*)&xrow[8]  = *(const float4*)&xp[8];
      *(float4*)&xrow[12] = *(const float4*)&xp[12];
      #pragma unroll
      for (int kx = 0; kx < 5; kx++) {
        const float w = wc[ky * 5 + kx];
        #pragma unroll
        for (int i = 0; i < 12; i++) acc[i] = fmaf(xrow[i + kx], w, acc[i]);
      }
    }
    #pragma unroll
    for (int i = 0; i < 12; i++) { a[tt * 12 + i] = acc[i]; asum += fabsf(acc[i]); }
  }

  float tot = blockReduceSumF(asum, red, tid, 8);
  float delta = (0.7f * tot) / 18432.0f;

  float msum = 0.0f, mcnt = 0.0f;
  #pragma unroll
  for (int i = 0; i < 36; i++) {
    float fa = fabsf(a[i]);
    if (fa > delta) { msum += fa; mcnt += 1.0f; }
  }
  float2 mm = blockReduceSum2F(msum, mcnt, red, tid, 8);
  if (tid == 0) alpha1[smp] = (mm.y > 0.0f) ? (mm.x / mm.y) : 0.0f;

  // packed sign stores: 12 bytes -> 3 dwords per tt.
  signed char* sp = s1full + (size_t)smp * 18432 + c * 576 + g * 12;
  #pragma unroll
  for (int tt = 0; tt < 3; tt++) {
    int s_[12];
    #pragma unroll
    for (int i = 0; i < 12; i++) {
      float v = a[tt * 12 + i];
      s_[i] = (v > delta) ? 1 : ((v < -delta) ? -1 : 0);
    }
    unsigned u0 = (s_[0] & 0xFF) | ((s_[1] & 0xFF) << 8) | ((s_[2] & 0xFF) << 16) |
                  (((unsigned)(s_[3] & 0xFF)) << 24);
    unsigned u1 = (s_[4] & 0xFF) | ((s_[5] & 0xFF) << 8) | ((s_[6] & 0xFF) << 16) |
                  (((unsigned)(s_[7] & 0xFF)) << 24);
    unsigned u2 = (s_[8] & 0xFF) | ((s_[9] & 0xFF) << 8) | ((s_[10] & 0xFF) << 16) |
                  (((unsigned)(s_[11] & 0xFF)) << 24);
    unsigned* wq = (unsigned*)(sp + tt * 192);
    wq[0] = u0; wq[1] = u1; wq[2] = u2;
  }
}

// ---------------- K2: BN1+maxpool+relu, conv2, ternarize ----
// R16: (a) launch_bounds (256,4)->(256,3) so the A/B weight double-buffer lives in
// registers (VGPR cap 128, still >=12 waves/CU = measured occupancy); (b) pooled phase
// divisionless: ci fixed per thread (tid>>3), incremental px/py. Per-element BN/max
// arithmetic and all conv FMA chains bitwise-identical to R15.
__device__ __forceinline__ void conv_body(const float* __restrict__ pb, int r0,
    float4 W0, float4 W1, float4 W2, float4 W3, float4 W4, float4 W5, float4 W6,
    float* __restrict__ acc0, float* __restrict__ acc1) {
  const float wk[25] = {W0.x, W0.y, W0.z, W0.w, W1.x, W1.y, W1.z, W1.w,
                        W2.x, W2.y, W2.z, W2.w, W3.x, W3.y, W3.z, W3.w,
                        W4.x, W4.y, W4.z, W4.w, W5.x, W5.y, W5.z, W5.w, W6.x};
  float rows[2][12];
  *(float4*)&rows[0][0] = *(const float4*)&pb[r0 * 12];
  *(float4*)&rows[0][4] = *(const float4*)&pb[r0 * 12 + 4];
  *(float4*)&rows[0][8] = *(const float4*)&pb[r0 * 12 + 8];
  #pragma unroll
  for (int ky = 0; ky < 5; ky++) {
    float* B = rows[(ky + 1) & 1];
    const float* bp = &pb[(r0 + ky + 1) * 12];
    *(float4*)&B[0] = *(const float4*)&bp[0];
    *(float4*)&B[4] = *(const float4*)&bp[4];
    *(float4*)&B[8] = *(const float4*)&bp[8];
    const float* A = rows[ky & 1];
    #pragma unroll
    for (int kx = 0; kx < 5; kx++) {
      const float w = wk[ky * 5 + kx];
      #pragma unroll
      for (int ox = 0; ox < 8; ox++) acc0[ox] = fmaf(A[ox + kx], w, acc0[ox]);
      #pragma unroll
      for (int ox = 0; ox < 8; ox++) acc1[ox] = fmaf(B[ox + kx], w, acc1[ox]);
    }
  }
}

__global__ __launch_bounds__(256, 3) void k2_conv2(
    const signed char* __restrict__ s1full, const float* __restrict__ alpha1,
    const float* __restrict__ w2t2, const float* __restrict__ b2,
    const float* __restrict__ g1, const float* __restrict__ bt1,
    signed char* __restrict__ s2full, float* __restrict__ alpha2) {
  __shared__ float pooled[4608];
  __shared__ float g1l[32], bt1l[32];
  __shared__ float red[32];

  const int tid = threadIdx.x;
  const int smp = blockIdx.x;
  const float BNINV = (float)(1.0 / sqrt(1.0 + 1e-5));

  if (tid < 32) { g1l[tid] = g1[tid] * BNINV; bt1l[tid] = bt1[tid]; }
  __syncthreads();

  const float a1 = alpha1[smp];
  {
    const int ci = tid >> 3;        // fixed channel per thread
    const int o8 = tid & 7;         // 18 elems per thread
    int r = o8 * 18;
    int py = (o8 * 3) >> 1;         // r/12
    int px = r - py * 12;
    const signed char* sbase = s1full + (size_t)smp * 18432 + ci * 576;
    float* pout = &pooled[ci * 144];
    const float gg = g1l[ci], bb = bt1l[ci];
    #pragma unroll
    for (int k = 0; k < 18; k++) {
      const signed char* sp = sbase + py * 48 + px * 2;
      char2 t0 = *(const char2*)sp;
      char2 t1 = *(const char2*)(sp + 24);
      float m = -1e30f;
      { float v = ((float)t0.x * a1) * gg + bb; m = (v > m) ? v : m; }
      { float v = ((float)t0.y * a1) * gg + bb; m = (v > m) ? v : m; }
      { float v = ((float)t1.x * a1) * gg + bb; m = (v > m) ? v : m; }
      { float v = ((float)t1.y * a1) * gg + bb; m = (v > m) ? v : m; }
      pout[py * 12 + px] = (m > 0.0f) ? m : 0.0f;
      px++;
      if (px == 12) { px = 0; py++; }
    }
  }
  __syncthreads();

  const int c2 = tid >> 2;
  const int q = tid & 3;
  const int r0 = q << 1;
  const float bias = b2[c2];
  float acc0[8], acc1[8];
  #pragma unroll
  for (int i = 0; i < 8; i++) { acc0[i] = bias; acc1[i] = bias; }

  const float4* wbase = ((const float4*)w2t2) + c2 * 7;  // 112 B/c2 -> 16B-aligned
  const float4* wp = wbase;
  float4 A0 = wp[0], A1 = wp[1], A2 = wp[2], A3 = wp[3], A4 = wp[4], A5 = wp[5], A6 = wp[6];
  #pragma unroll 1
  for (int cc = 0; cc < 32; cc += 2) {
    const float4* wn = wp + 448;  // cc+1 slab (448 float4 = 64 c2 * 7)
    float4 B0 = wn[0], B1 = wn[1], B2 = wn[2], B3 = wn[3], B4 = wn[4], B5 = wn[5], B6 = wn[6];
    conv_body(&pooled[cc * 144], r0, A0, A1, A2, A3, A4, A5, A6, acc0, acc1);
    const float4* wn2 = (cc < 30) ? (wp + 896) : wbase;  // cc+2 (dummy reload at tail)
    A0 = wn2[0]; A1 = wn2[1]; A2 = wn2[2]; A3 = wn2[3]; A4 = wn2[4]; A5 = wn2[5]; A6 = wn2[6];
    conv_body(&pooled[(cc + 1) * 144], r0, B0, B1, B2, B3, B4, B5, B6, acc0, acc1);
    wp += 896;
  }

  float asum = 0.0f;
  #pragma unroll
  for (int i = 0; i < 8; i++) asum += fabsf(acc0[i]) + fabsf(acc1[i]);
  float tot = blockReduceSumF(asum, red, tid, 4);
  float delta = (0.7f * tot) / 4096.0f;

  float msum = 0.0f, mcnt = 0.0f;
  #pragma unroll
  for (int i = 0; i < 8; i++) {
    float f0 = fabsf(acc0[i]);
    if (f0 > delta) { msum += f0; mcnt += 1.0f; }
    float f1 = fabsf(acc1[i]);
    if (f1 > delta) { msum += f1; mcnt += 1.0f; }
  }
  float2 mm = blockReduceSum2F(msum, mcnt, red, tid, 4);
  if (tid == 0) alpha2[smp] = (mm.y > 0.0f) ? (mm.x / mm.y) : 0.0f;

  // pack 16 sign bytes -> one uint4 store (16B-aligned: r0 even).
  int t_[16];
  #pragma unroll
  for (int ox = 0; ox < 8; ox++) {
    float v = acc0[ox];
    t_[ox] = (v > delta) ? 1 : ((v < -delta) ? -1 : 0);
  }
  #pragma unroll
  for (int ox = 0; ox < 8; ox++) {
    float v = acc1[ox];
    t_[8 + ox] = (v > delta) ? 1 : ((v < -delta) ? -1 : 0);
  }
  unsigned u0 = (t_[0] & 0xFF) | ((t_[1] & 0xFF) << 8) | ((t_[2] & 0xFF) << 16) |
                (((unsigned)(t_[3] & 0xFF)) << 24);
  unsigned u1 = (t_[4] & 0xFF) | ((t_[5] & 0xFF) << 8) | ((t_[6] & 0xFF) << 16) |
                (((unsigned)(t_[7] & 0xFF)) << 24);
  unsigned u2 = (t_[8] & 0xFF) | ((t_[9] & 0xFF) << 8) | ((t_[10] & 0xFF) << 16) |
                (((unsigned)(t_[11] & 0xFF)) << 24);
  unsigned u3 = (t_[12] & 0xFF) | ((t_[13] & 0xFF) << 8) | ((t_[14] & 0xFF) << 16) |
                (((unsigned)(t_[15] & 0xFF)) << 24);
  *(uint4*)(s2full + (size_t)smp * 4096 + c2 * 64 + r0 * 8) = make_uint4(u0, u1, u2, u3);
}

// ---------------- K0t: transpose fc1 weights into w1t[k][o] (into dead s1full) ----------
__global__ void k0_transpose(const float* __restrict__ w1f, float* __restrict__ w1t) {
  int i = blockIdx.x * 256 + threadIdx.x;  // i over 524288
  int k = i >> 9;
  int o = i & 511;
  w1t[i] = w1f[o * 1024 + k];
}

// ---------------- K3: 4 samples/block; fc1 via transposed weights ----
__global__ __launch_bounds__(1024, 4) void k3_fc(
    const signed char* __restrict__ s2full, const float* __restrict__ alpha2,
    const float* __restrict__ w1t, const float* __restrict__ f1b,
    const float* __restrict__ w2f, const float* __restrict__ f2b,
    const float* __restrict__ g2, const float* __restrict__ bt2,
    float* __restrict__ out) {
  __shared__ float S[16384];
  __shared__ float fco[4][512];
  __shared__ float g2l[64], bt2l[64];
  __shared__ float redm[4][4];
  __shared__ float out2[4][10];

  const int tid = threadIdx.x;
  const int blk = blockIdx.x;
  const float BNINV = (float)(1.0 / sqrt(1.0 + 1e-5));

  if (tid < 64) { g2l[tid] = g2[tid] * BNINV; bt2l[tid] = bt2[tid]; }
  __syncthreads();

  float* h4 = S;
  for (int e = tid; e < 4096; e += 1024) {
    int j = e >> 2;
    int s = e & 3;
    int cc = j >> 4;
    int r = j & 15;
    int py = r >> 2;
    int px = r & 3;
    const signed char* sp = s2full + (size_t)(blk * 4 + s) * 4096 + cc * 64 + (py * 2) * 8 + px * 2;
    float a2 = alpha2[blk * 4 + s];
    float m = -1e30f;
    #pragma unroll
    for (int dy = 0; dy < 2; dy++)
      #pragma unroll
      for (int dx = 0; dx < 2; dx++) {
        float v = ((float)sp[dy * 8 + dx] * a2) * g2l[cc] + bt2l[cc];
        m = (v > m) ? v : m;
      }
    h4[j * 4 + s] = (m > 0.0f) ? m : 0.0f;
  }
  __syncthreads();

  const int kp = tid >> 7;
  const int og = tid & 127;
  float a00=0,a01=0,a02=0,a03=0, a10=0,a11=0,a12=0,a13=0;
  float a20=0,a21=0,a22=0,a23=0, a30=0,a31=0,a32=0,a33=0;
  const float4* w4 = (const float4*)w1t;
  const float4* h44 = (const float4*)h4;
  const int kbase = kp << 7;
  for (int kk = 0; kk < 128; kk++) {
    const int k = kbase + kk;
    const float4 wv = w4[(k << 7) + og];
    const float4 hv = h44[k];
    a00 = fmaf(hv.x, wv.x, a00); a01 = fmaf(hv.y, wv.x, a01);
    a02 = fmaf(hv.z, wv.x, a02); a03 = fmaf(hv.w, wv.x, a03);
    a10 = fmaf(hv.x, wv.y, a10); a11 = fmaf(hv.y, wv.y, a11);
    a12 = fmaf(hv.z, wv.y, a12); a13 = fmaf(hv.w, wv.y, a13);
    a20 = fmaf(hv.x, wv.z, a20); a21 = fmaf(hv.y, wv.z, a21);
    a22 = fmaf(hv.z, wv.z, a22); a23 = fmaf(hv.w, wv.z, a23);
    a30 = fmaf(hv.x, wv.w, a30); a31 = fmaf(hv.y, wv.w, a31);
    a32 = fmaf(hv.z, wv.w, a32); a33 = fmaf(hv.w, wv.w, a33);
  }
  __syncthreads();
  {
    float4* p4 = (float4*)S;
    const int base = (kp << 9) + (og << 2);
    p4[base + 0] = make_float4(a00, a01, a02, a03);
    p4[base + 1] = make_float4(a10, a11, a12, a13);
    p4[base + 2] = make_float4(a20, a21, a22, a23);
    p4[base + 3] = make_float4(a30, a31, a32, a33);
  }
  __syncthreads();

  for (int p = tid; p < 2048; p += 1024) {
    int o = p >> 2;
    int s = p & 3;
    float v = S[p];
    #pragma unroll
    for (int kp2 = 1; kp2 < 8; kp2++) v += S[kp2 * 2048 + p];
    fco[s][o] = v + f1b[o];
  }
  __syncthreads();

  float (*h3)[512] = (float(*)[512])S;
  const int sg = tid >> 8;
  const int tj = tid & 255;
  float v0 = fco[sg][tj];
  float v1 = fco[sg][tj + 256];
  float av0 = fabsf(v0), av1 = fabsf(v1);
  float tot = groupReduce4w(av0 + av1, redm[sg], tj);
  float delta = (0.7f * tot) / 512.0f;
  float m0 = (av0 > delta) ? av0 : 0.0f;
  float m1 = (av1 > delta) ? av1 : 0.0f;
  float msum = groupReduce4w(m0 + m1, redm[sg], tj);
  float mcnt = groupReduce4w(((av0 > delta) ? 1.0f : 0.0f) + ((av1 > delta) ? 1.0f : 0.0f),
                             redm[sg], tj);
  float alpha3 = (mcnt > 0.0f) ? (msum / mcnt) : 0.0f;
  {
    float t0 = (v0 > delta) ? 1.0f : ((v0 < -delta) ? -1.0f : 0.0f);
    float hv0 = t0 * alpha3;
    h3[sg][tj] = (hv0 > 0.0f) ? hv0 : 0.0f;
    float t1 = (v1 > delta) ? 1.0f : ((v1 < -delta) ? -1.0f : 0.0f);
    float hv1 = t1 * alpha3;
    h3[sg][tj + 256] = (hv1 > 0.0f) ? hv1 : 0.0f;
  }
  __syncthreads();

  const int lane = tid & 63;
  const int wid = tid >> 6;
  for (int t = wid; t < 40; t += 16) {
    int s = t / 10;
    int o = t - s * 10;
    float acc = 0.0f;
    #pragma unroll
    for (int m = 0; m < 8; m++) {
      int j = lane + (m << 6);
      acc = fmaf(h3[s][j], w2f[o * 512 + j], acc);
    }
    #pragma unroll
    for (int off = 32; off > 0; off >>= 1) acc += __shfl_xor(acc, off);
    if (lane == 0) out2[s][o] = acc + f2b[o];
  }
  __syncthreads();

  if (tid < 4) {
    int s = tid;
    float t2 = 0.0f;
    for (int i = 0; i < 10; i++) t2 += fabsf(out2[s][i]);
    float d = (0.7f * t2) / 10.0f;
    float ms = 0.0f, mc = 0.0f;
    for (int i = 0; i < 10; i++) {
      float a = fabsf(out2[s][i]);
      if (a > d) { ms += a; mc += 1.0f; }
    }
    float al = (mc > 0.0f) ? (ms / mc) : 0.0f;
    for (int i = 0; i < 10; i++) {
      float vv = out2[s][i];
      float sv = (vv > d) ? 1.0f : ((vv < -d) ? -1.0f : 0.0f);
      out[(size_t)(blk * 4 + s) * 10 + i] = sv * al;
    }
  }
}

// assumption-violation marker
__global__ void k_marker(float* __restrict__ out, int n, float val) {
  int i = blockIdx.x * 256 + threadIdx.x;
  if (i < n) out[i] = val;
}

extern "C" void kernel_launch(void* const* d_in, const int* in_sizes, int n_in,
                              void* d_out, int out_size, void* d_ws, size_t ws_size,
                              hipStream_t stream) {
  float* out = (float*)d_out;

  static const int expect[13] = {1605632, 800, 32, 32, 32, 51200, 64, 64, 64,
                                 524288, 512, 5120, 10};
  float marker = 0.0f;
  if (n_in != 13) marker = 304.0f;
  else {
    for (int i = 0; i < 13; i++)
      if (in_sizes[i] != expect[i]) { marker = 320.0f + 16.0f * i; break; }
  }
  if (marker == 0.0f && out_size != 20480) marker = 560.0f;

  float* alpha1 = (float*)d_ws;                           // 2048
  float* alpha2 = alpha1 + BATCH;                         // 2048
  float* w2t2   = alpha2 + BATCH;                         // 57344 (229 KB, padded)
  signed char* s1full = (signed char*)(w2t2 + 57344);     // 2048*18432 (dead after k2;
                                                          //  first 2MB reused as w1t)
  signed char* s2full = s1full + (size_t)BATCH * 18432;   // 2048*4096
  size_t needed = (size_t)((s2full + (size_t)BATCH * 4096) - (signed char*)d_ws);
  if (marker == 0.0f && ws_size < needed) marker = 576.0f;

  if (marker != 0.0f) {
    k_marker<<<dim3((out_size + 255) / 256), dim3(256), 0, stream>>>(out, out_size, marker);
    return;
  }

  const float* x   = (const float*)d_in[0];
  const float* c1w = (const float*)d_in[1];
  const float* c1b = (const float*)d_in[2];
  const float* g1  = (const float*)d_in[3];
  const float* bt1 = (const float*)d_in[4];
  const float* c2w = (const float*)d_in[5];
  const float* c2b = (const float*)d_in[6];
  const float* g2  = (const float*)d_in[7];
  const float* bt2 = (const float*)d_in[8];
  const float* f1w = (const float*)d_in[9];
  const float* f1b = (const float*)d_in[10];
  const float* f2w = (const float*)d_in[11];
  const float* f2b = (const float*)d_in[12];

  float* w1t = (float*)s1full;

  k0_w2t<<<dim3(224), dim3(256), 0, stream>>>(c2w, w2t2);
  k1_conv1<<<dim3(BATCH), dim3(512), 0, stream>>>(x, c1w, c1b, s1full, alpha1);
  k2_conv2<<<dim3(BATCH), dim3(256), 0, stream>>>(s1full, alpha1, w2t2, c2b, g1, bt1, s2full, alpha2);
  k0_transpose<<<dim3(2048), dim3(256), 0, stream>>>(f1w, w1t);
  k3_fc<<<dim3(BATCH / 4), dim3(1024), 0, stream>>>(s2full, alpha2, w1t, f1b, f2w, f2b, g2, bt2, out);
}

// Round 3
// 347.057 us; speedup vs baseline: 1.3232x; 1.0054x over previous
//
#include <hip/hip_runtime.h>

#define BATCH 2048

// block-wide f32 sum; all threads get the result. red >= 32 floats.
__device__ __forceinline__ float blockReduceSumF(float v, float* red, int tid, int nwaves) {
  #pragma unroll
  for (int off = 32; off > 0; off >>= 1) v += __shfl_xor(v, off);
  __syncthreads();
  if ((tid & 63) == 0) red[tid >> 6] = v;
  __syncthreads();
  if (tid == 0) {
    float s = red[0];
    for (int i = 1; i < nwaves; i++) s += red[i];
    red[31] = s;
  }
  __syncthreads();
  return red[31];
}

// packed 2-value block reduce (one barrier sequence); per-component order identical
// to two sequential blockReduceSumF calls -> bit-exact. red >= 32 floats; nwaves <= 8.
__device__ __forceinline__ float2 blockReduceSum2F(float a, float b, float* red, int tid, int nwaves) {
  #pragma unroll
  for (int off = 32; off > 0; off >>= 1) { a += __shfl_xor(a, off); b += __shfl_xor(b, off); }
  __syncthreads();
  if ((tid & 63) == 0) { red[tid >> 6] = a; red[(tid >> 6) + 16] = b; }
  __syncthreads();
  if (tid == 0) {
    float sa = red[0], sb = red[16];
    for (int i = 1; i < nwaves; i++) { sa += red[i]; sb += red[16 + i]; }
    red[30] = sa; red[31] = sb;
  }
  __syncthreads();
  return make_float2(red[30], red[31]);
}

// 4-wave (256-thread) group reduce; seg = 4-float LDS segment for this group.
__device__ __forceinline__ float groupReduce4w(float v, float* seg, int tj) {
  #pragma unroll
  for (int off = 32; off > 0; off >>= 1) v += __shfl_xor(v, off);
  __syncthreads();
  if ((tj & 63) == 0) seg[tj >> 6] = v;
  __syncthreads();
  return (seg[0] + seg[1]) + (seg[2] + seg[3]);
}

// ---------------- K0a: pack conv2 weights -> w2t2[cc][c2][28] (229 KB) ----------------
__global__ void k0_w2t(const float* __restrict__ w2, float* __restrict__ w2t2) {
  int i = blockIdx.x * 256 + threadIdx.x;  // over 57344
  if (i >= 57344) return;
  int cc = i / 1792;
  int r = i - cc * 1792;
  int c2 = r / 28;
  int k = r - c2 * 28;
  w2t2[i] = (k < 25) ? w2[c2 * 800 + cc * 25 + k] : 0.0f;
}

// ---------------- K1: conv1 + ternarize -> sign map + alpha1 (f32) ----------------
// (512,4): VGPR cap 128, 2 blocks/CU — no spill (R16 fix, confirmed R2).
__global__ __launch_bounds__(512, 4) void k1_conv1(
    const float* __restrict__ x, const float* __restrict__ w1, const float* __restrict__ b1,
    signed char* __restrict__ s1full, float* __restrict__ alpha1) {
  __shared__ float xs[784];
  __shared__ float wsm[800];
  __shared__ float red[32];

  const int tid = threadIdx.x;
  const int smp = blockIdx.x;

  for (int j = tid; j < 784; j += 512) xs[j] = x[smp * 784 + j];
  for (int j = tid; j < 800; j += 512) wsm[j] = w1[j];
  __syncthreads();

  const int c = tid >> 4;
  const int g = tid & 15;
  const float bias = b1[c];
  const float* wc = &wsm[c * 25];

  float a[36];
  float asum = 0.0f;
  #pragma unroll
  for (int tt = 0; tt < 3; tt++) {
    const int t = g + (tt << 4);
    const int r = t >> 1;
    const int hx = (t & 1) * 12;
    float acc[12];
    #pragma unroll
    for (int i = 0; i < 12; i++) acc[i] = bias;
    #pragma unroll
    for (int ky = 0; ky < 5; ky++) {
      const float* xp = &xs[(r + ky) * 28 + hx];
      float xrow[16];
      *(float4*)&xrow[0]  = *(const float4*)&xp[0];
      *(float4*)&xrow[4]  = *(const float4*)&xp[4];
      *(float4*)&xrow[8]  = *(const float4*)&xp[8];
      *(float4*)&xrow[12] = *(const float4*)&xp[12];
      #pragma unroll
      for (int kx = 0; kx < 5; kx++) {
        const float w = wc[ky * 5 + kx];
        #pragma unroll
        for (int i = 0; i < 12; i++) acc[i] = fmaf(xrow[i + kx], w, acc[i]);
      }
    }
    #pragma unroll
    for (int i = 0; i < 12; i++) { a[tt * 12 + i] = acc[i]; asum += fabsf(acc[i]); }
  }

  float tot = blockReduceSumF(asum, red, tid, 8);
  float delta = (0.7f * tot) / 18432.0f;

  float msum = 0.0f, mcnt = 0.0f;
  #pragma unroll
  for (int i = 0; i < 36; i++) {
    float fa = fabsf(a[i]);
    if (fa > delta) { msum += fa; mcnt += 1.0f; }
  }
  float2 mm = blockReduceSum2F(msum, mcnt, red, tid, 8);
  if (tid == 0) alpha1[smp] = (mm.y > 0.0f) ? (mm.x / mm.y) : 0.0f;

  // packed sign stores: 12 bytes -> 3 dwords per tt.
  signed char* sp = s1full + (size_t)smp * 18432 + c * 576 + g * 12;
  #pragma unroll
  for (int tt = 0; tt < 3; tt++) {
    int s_[12];
    #pragma unroll
    for (int i = 0; i < 12; i++) {
      float v = a[tt * 12 + i];
      s_[i] = (v > delta) ? 1 : ((v < -delta) ? -1 : 0);
    }
    unsigned u0 = (s_[0] & 0xFF) | ((s_[1] & 0xFF) << 8) | ((s_[2] & 0xFF) << 16) |
                  (((unsigned)(s_[3] & 0xFF)) << 24);
    unsigned u1 = (s_[4] & 0xFF) | ((s_[5] & 0xFF) << 8) | ((s_[6] & 0xFF) << 16) |
                  (((unsigned)(s_[7] & 0xFF)) << 24);
    unsigned u2 = (s_[8] & 0xFF) | ((s_[9] & 0xFF) << 8) | ((s_[10] & 0xFF) << 16) |
                  (((unsigned)(s_[11] & 0xFF)) << 24);
    unsigned* wq = (unsigned*)(sp + tt * 192);
    wq[0] = u0; wq[1] = u1; wq[2] = u2;
  }
}

// ---------------- K2: BN1+maxpool+relu, conv2, ternarize ----
// R17: streaming-row inner loop. Per cc, rows t=0..5 pass once through ONE 12-float
// buffer; row t feeds acc0 at ky=t and acc1 at ky=t-1. Deletes rows[2][12] rotation and
// the A/B weight double-buffer (R1 measured them as +20us of VALU movs, no latency win).
// Per-accumulator FMA chain order (ky asc, kx asc) and all reductions bitwise-identical
// to R15/R16.
__global__ __launch_bounds__(256, 3) void k2_conv2(
    const signed char* __restrict__ s1full, const float* __restrict__ alpha1,
    const float* __restrict__ w2t2, const float* __restrict__ b2,
    const float* __restrict__ g1, const float* __restrict__ bt1,
    signed char* __restrict__ s2full, float* __restrict__ alpha2) {
  __shared__ float pooled[4608];
  __shared__ float g1l[32], bt1l[32];
  __shared__ float red[32];

  const int tid = threadIdx.x;
  const int smp = blockIdx.x;
  const float BNINV = (float)(1.0 / sqrt(1.0 + 1e-5));

  if (tid < 32) { g1l[tid] = g1[tid] * BNINV; bt1l[tid] = bt1[tid]; }
  __syncthreads();

  const float a1 = alpha1[smp];
  {
    const int ci = tid >> 3;        // fixed channel per thread
    const int o8 = tid & 7;         // 18 elems per thread
    int r = o8 * 18;
    int py = (o8 * 3) >> 1;         // r/12
    int px = r - py * 12;
    const signed char* sbase = s1full + (size_t)smp * 18432 + ci * 576;
    float* pout = &pooled[ci * 144];
    const float gg = g1l[ci], bb = bt1l[ci];
    #pragma unroll
    for (int k = 0; k < 18; k++) {
      const signed char* sp = sbase + py * 48 + px * 2;
      char2 t0 = *(const char2*)sp;
      char2 t1 = *(const char2*)(sp + 24);
      float m = -1e30f;
      { float v = ((float)t0.x * a1) * gg + bb; m = (v > m) ? v : m; }
      { float v = ((float)t0.y * a1) * gg + bb; m = (v > m) ? v : m; }
      { float v = ((float)t1.x * a1) * gg + bb; m = (v > m) ? v : m; }
      { float v = ((float)t1.y * a1) * gg + bb; m = (v > m) ? v : m; }
      pout[py * 12 + px] = (m > 0.0f) ? m : 0.0f;
      px++;
      if (px == 12) { px = 0; py++; }
    }
  }
  __syncthreads();

  const int c2 = tid >> 2;
  const int q = tid & 3;
  const int r0 = q << 1;
  const float bias = b2[c2];
  float acc0[8], acc1[8];
  #pragma unroll
  for (int i = 0; i < 8; i++) { acc0[i] = bias; acc1[i] = bias; }

  const float4* wp = ((const float4*)w2t2) + c2 * 7;  // 112 B/c2 -> 16B-aligned
  const float* pb = &pooled[r0 * 12];
  #pragma unroll 1
  for (int cc = 0; cc < 32; cc++) {
    const float4 W0 = wp[0], W1 = wp[1], W2 = wp[2], W3 = wp[3],
                 W4 = wp[4], W5 = wp[5], W6 = wp[6];
    const float wk[25] = {W0.x, W0.y, W0.z, W0.w, W1.x, W1.y, W1.z, W1.w,
                          W2.x, W2.y, W2.z, W2.w, W3.x, W3.y, W3.z, W3.w,
                          W4.x, W4.y, W4.z, W4.w, W5.x, W5.y, W5.z, W5.w, W6.x};
    #pragma unroll
    for (int t = 0; t < 6; t++) {
      float row[12];
      *(float4*)&row[0] = *(const float4*)&pb[t * 12];
      *(float4*)&row[4] = *(const float4*)&pb[t * 12 + 4];
      *(float4*)&row[8] = *(const float4*)&pb[t * 12 + 8];
      #pragma unroll
      for (int ky = 0; ky < 5; ky++) {
        const int i = t - ky;          // compile-time after unroll
        if (i == 0) {
          #pragma unroll
          for (int kx = 0; kx < 5; kx++) {
            const float w = wk[ky * 5 + kx];
            #pragma unroll
            for (int ox = 0; ox < 8; ox++) acc0[ox] = fmaf(row[ox + kx], w, acc0[ox]);
          }
        } else if (i == 1) {
          #pragma unroll
          for (int kx = 0; kx < 5; kx++) {
            const float w = wk[ky * 5 + kx];
            #pragma unroll
            for (int ox = 0; ox < 8; ox++) acc1[ox] = fmaf(row[ox + kx], w, acc1[ox]);
          }
        }
      }
    }
    wp += 448;   // next cc slab (64 c2 * 7 float4)
    pb += 144;   // next channel plane
  }

  float asum = 0.0f;
  #pragma unroll
  for (int i = 0; i < 8; i++) asum += fabsf(acc0[i]) + fabsf(acc1[i]);
  float tot = blockReduceSumF(asum, red, tid, 4);
  float delta = (0.7f * tot) / 4096.0f;

  float msum = 0.0f, mcnt = 0.0f;
  #pragma unroll
  for (int i = 0; i < 8; i++) {
    float f0 = fabsf(acc0[i]);
    if (f0 > delta) { msum += f0; mcnt += 1.0f; }
    float f1 = fabsf(acc1[i]);
    if (f1 > delta) { msum += f1; mcnt += 1.0f; }
  }
  float2 mm = blockReduceSum2F(msum, mcnt, red, tid, 4);
  if (tid == 0) alpha2[smp] = (mm.y > 0.0f) ? (mm.x / mm.y) : 0.0f;

  // pack 16 sign bytes -> one uint4 store (16B-aligned: r0 even).
  int t_[16];
  #pragma unroll
  for (int ox = 0; ox < 8; ox++) {
    float v = acc0[ox];
    t_[ox] = (v > delta) ? 1 : ((v < -delta) ? -1 : 0);
  }
  #pragma unroll
  for (int ox = 0; ox < 8; ox++) {
    float v = acc1[ox];
    t_[8 + ox] = (v > delta) ? 1 : ((v < -delta) ? -1 : 0);
  }
  unsigned u0 = (t_[0] & 0xFF) | ((t_[1] & 0xFF) << 8) | ((t_[2] & 0xFF) << 16) |
                (((unsigned)(t_[3] & 0xFF)) << 24);
  unsigned u1 = (t_[4] & 0xFF) | ((t_[5] & 0xFF) << 8) | ((t_[6] & 0xFF) << 16) |
                (((unsigned)(t_[7] & 0xFF)) << 24);
  unsigned u2 = (t_[8] & 0xFF) | ((t_[9] & 0xFF) << 8) | ((t_[10] & 0xFF) << 16) |
                (((unsigned)(t_[11] & 0xFF)) << 24);
  unsigned u3 = (t_[12] & 0xFF) | ((t_[13] & 0xFF) << 8) | ((t_[14] & 0xFF) << 16) |
                (((unsigned)(t_[15] & 0xFF)) << 24);
  *(uint4*)(s2full + (size_t)smp * 4096 + c2 * 64 + r0 * 8) = make_uint4(u0, u1, u2, u3);
}

// ---------------- K0t: transpose fc1 weights into w1t[k][o] (into dead s1full) ----------
__global__ void k0_transpose(const float* __restrict__ w1f, float* __restrict__ w1t) {
  int i = blockIdx.x * 256 + threadIdx.x;  // i over 524288
  int k = i >> 9;
  int o = i & 511;
  w1t[i] = w1f[o * 1024 + k];
}

// ---------------- K3: 4 samples/block; fc1 via transposed weights ----
__global__ __launch_bounds__(1024, 4) void k3_fc(
    const signed char* __restrict__ s2full, const float* __restrict__ alpha2,
    const float* __restrict__ w1t, const float* __restrict__ f1b,
    const float* __restrict__ w2f, const float* __restrict__ f2b,
    const float* __restrict__ g2, const float* __restrict__ bt2,
    float* __restrict__ out) {
  __shared__ float S[16384];
  __shared__ float fco[4][512];
  __shared__ float g2l[64], bt2l[64];
  __shared__ float redm[4][4];
  __shared__ float out2[4][10];

  const int tid = threadIdx.x;
  const int blk = blockIdx.x;
  const float BNINV = (float)(1.0 / sqrt(1.0 + 1e-5));

  if (tid < 64) { g2l[tid] = g2[tid] * BNINV; bt2l[tid] = bt2[tid]; }
  __syncthreads();

  float* h4 = S;
  for (int e = tid; e < 4096; e += 1024) {
    int j = e >> 2;
    int s = e & 3;
    int cc = j >> 4;
    int r = j & 15;
    int py = r >> 2;
    int px = r & 3;
    const signed char* sp = s2full + (size_t)(blk * 4 + s) * 4096 + cc * 64 + (py * 2) * 8 + px * 2;
    float a2 = alpha2[blk * 4 + s];
    float m = -1e30f;
    #pragma unroll
    for (int dy = 0; dy < 2; dy++)
      #pragma unroll
      for (int dx = 0; dx < 2; dx++) {
        float v = ((float)sp[dy * 8 + dx] * a2) * g2l[cc] + bt2l[cc];
        m = (v > m) ? v : m;
      }
    h4[j * 4 + s] = (m > 0.0f) ? m : 0.0f;
  }
  __syncthreads();

  const int kp = tid >> 7;
  const int og = tid & 127;
  float a00=0,a01=0,a02=0,a03=0, a10=0,a11=0,a12=0,a13=0;
  float a20=0,a21=0,a22=0,a23=0, a30=0,a31=0,a32=0,a33=0;
  const float4* w4 = (const float4*)w1t;
  const float4* h44 = (const float4*)h4;
  const int kbase = kp << 7;
  for (int kk = 0; kk < 128; kk++) {
    const int k = kbase + kk;
    const float4 wv = w4[(k << 7) + og];
    const float4 hv = h44[k];
    a00 = fmaf(hv.x, wv.x, a00); a01 = fmaf(hv.y, wv.x, a01);
    a02 = fmaf(hv.z, wv.x, a02); a03 = fmaf(hv.w, wv.x, a03);
    a10 = fmaf(hv.x, wv.y, a10); a11 = fmaf(hv.y, wv.y, a11);
    a12 = fmaf(hv.z, wv.y, a12); a13 = fmaf(hv.w, wv.y, a13);
    a20 = fmaf(hv.x, wv.z, a20); a21 = fmaf(hv.y, wv.z, a21);
    a22 = fmaf(hv.z, wv.z, a22); a23 = fmaf(hv.w, wv.z, a23);
    a30 = fmaf(hv.x, wv.w, a30); a31 = fmaf(hv.y, wv.w, a31);
    a32 = fmaf(hv.z, wv.w, a32); a33 = fmaf(hv.w, wv.w, a33);
  }
  __syncthreads();
  {
    float4* p4 = (float4*)S;
    const int base = (kp << 9) + (og << 2);
    p4[base + 0] = make_float4(a00, a01, a02, a03);
    p4[base + 1] = make_float4(a10, a11, a12, a13);
    p4[base + 2] = make_float4(a20, a21, a22, a23);
    p4[base + 3] = make_float4(a30, a31, a32, a33);
  }
  __syncthreads();

  for (int p = tid; p < 2048; p += 1024) {
    int o = p >> 2;
    int s = p & 3;
    float v = S[p];
    #pragma unroll
    for (int kp2 = 1; kp2 < 8; kp2++) v += S[kp2 * 2048 + p];
    fco[s][o] = v + f1b[o];
  }
  __syncthreads();

  float (*h3)[512] = (float(*)[512])S;
  const int sg = tid >> 8;
  const int tj = tid & 255;
  float v0 = fco[sg][tj];
  float v1 = fco[sg][tj + 256];
  float av0 = fabsf(v0), av1 = fabsf(v1);
  float tot = groupReduce4w(av0 + av1, redm[sg], tj);
  float delta = (0.7f * tot) / 512.0f;
  float m0 = (av0 > delta) ? av0 : 0.0f;
  float m1 = (av1 > delta) ? av1 : 0.0f;
  float msum = groupReduce4w(m0 + m1, redm[sg], tj);
  float mcnt = groupReduce4w(((av0 > delta) ? 1.0f : 0.0f) + ((av1 > delta) ? 1.0f : 0.0f),
                             redm[sg], tj);
  float alpha3 = (mcnt > 0.0f) ? (msum / mcnt) : 0.0f;
  {
    float t0 = (v0 > delta) ? 1.0f : ((v0 < -delta) ? -1.0f : 0.0f);
    float hv0 = t0 * alpha3;
    h3[sg][tj] = (hv0 > 0.0f) ? hv0 : 0.0f;
    float t1 = (v1 > delta) ? 1.0f : ((v1 < -delta) ? -1.0f : 0.0f);
    float hv1 = t1 * alpha3;
    h3[sg][tj + 256] = (hv1 > 0.0f) ? hv1 : 0.0f;
  }
  __syncthreads();

  const int lane = tid & 63;
  const int wid = tid >> 6;
  for (int t = wid; t < 40; t += 16) {
    int s = t / 10;
    int o = t - s * 10;
    float acc = 0.0f;
    #pragma unroll
    for (int m = 0; m < 8; m++) {
      int j = lane + (m << 6);
      acc = fmaf(h3[s][j], w2f[o * 512 + j], acc);
    }
    #pragma unroll
    for (int off = 32; off > 0; off >>= 1) acc += __shfl_xor(acc, off);
    if (lane == 0) out2[s][o] = acc + f2b[o];
  }
  __syncthreads();

  if (tid < 4) {
    int s = tid;
    float t2 = 0.0f;
    for (int i = 0; i < 10; i++) t2 += fabsf(out2[s][i]);
    float d = (0.7f * t2) / 10.0f;
    float ms = 0.0f, mc = 0.0f;
    for (int i = 0; i < 10; i++) {
      float a = fabsf(out2[s][i]);
      if (a > d) { ms += a; mc += 1.0f; }
    }
    float al = (mc > 0.0f) ? (ms / mc) : 0.0f;
    for (int i = 0; i < 10; i++) {
      float vv = out2[s][i];
      float sv = (vv > d) ? 1.0f : ((vv < -d) ? -1.0f : 0.0f);
      out[(size_t)(blk * 4 + s) * 10 + i] = sv * al;
    }
  }
}

// assumption-violation marker
__global__ void k_marker(float* __restrict__ out, int n, float val) {
  int i = blockIdx.x * 256 + threadIdx.x;
  if (i < n) out[i] = val;
}

extern "C" void kernel_launch(void* const* d_in, const int* in_sizes, int n_in,
                              void* d_out, int out_size, void* d_ws, size_t ws_size,
                              hipStream_t stream) {
  float* out = (float*)d_out;

  static const int expect[13] = {1605632, 800, 32, 32, 32, 51200, 64, 64, 64,
                                 524288, 512, 5120, 10};
  float marker = 0.0f;
  if (n_in != 13) marker = 304.0f;
  else {
    for (int i = 0; i < 13; i++)
      if (in_sizes[i] != expect[i]) { marker = 320.0f + 16.0f * i; break; }
  }
  if (marker == 0.0f && out_size != 20480) marker = 560.0f;

  float* alpha1 = (float*)d_ws;                           // 2048
  float* alpha2 = alpha1 + BATCH;                         // 2048
  float* w2t2   = alpha2 + BATCH;                         // 57344 (229 KB, padded)
  signed char* s1full = (signed char*)(w2t2 + 57344);     // 2048*18432 (dead after k2;
                                                          //  first 2MB reused as w1t)
  signed char* s2full = s1full + (size_t)BATCH * 18432;   // 2048*4096
  size_t needed = (size_t)((s2full + (size_t)BATCH * 4096) - (signed char*)d_ws);
  if (marker == 0.0f && ws_size < needed) marker = 576.0f;

  if (marker != 0.0f) {
    k_marker<<<dim3((out_size + 255) / 256), dim3(256), 0, stream>>>(out, out_size, marker);
    return;
  }

  const float* x   = (const float*)d_in[0];
  const float* c1w = (const float*)d_in[1];
  const float* c1b = (const float*)d_in[2];
  const float* g1  = (const float*)d_in[3];
  const float* bt1 = (const float*)d_in[4];
  const float* c2w = (const float*)d_in[5];
  const float* c2b = (const float*)d_in[6];
  const float* g2  = (const float*)d_in[7];
  const float* bt2 = (const float*)d_in[8];
  const float* f1w = (const float*)d_in[9];
  const float* f1b = (const float*)d_in[10];
  const float* f2w = (const float*)d_in[11];
  const float* f2b = (const float*)d_in[12];

  float* w1t = (float*)s1full;

  k0_w2t<<<dim3(224), dim3(256), 0, stream>>>(c2w, w2t2);
  k1_conv1<<<dim3(BATCH), dim3(512), 0, stream>>>(x, c1w, c1b, s1full, alpha1);
  k2_conv2<<<dim3(BATCH), dim3(256), 0, stream>>>(s1full, alpha1, w2t2, c2b, g1, bt1, s2full, alpha2);
  k0_transpose<<<dim3(2048), dim3(256), 0, stream>>>(f1w, w1t);
  k3_fc<<<dim3(BATCH / 4), dim3(1024), 0, stream>>>(s2full, alpha2, w1t, f1b, f2w, f2b, g2, bt2, out);
}

// Round 4
// 320.788 us; speedup vs baseline: 1.4316x; 1.0819x over previous
//
#include <hip/hip_runtime.h>

#define BATCH 2048

// block-wide f32 sum; all threads get the result. red >= 32 floats.
__device__ __forceinline__ float blockReduceSumF(float v, float* red, int tid, int nwaves) {
  #pragma unroll
  for (int off = 32; off > 0; off >>= 1) v += __shfl_xor(v, off);
  __syncthreads();
  if ((tid & 63) == 0) red[tid >> 6] = v;
  __syncthreads();
  if (tid == 0) {
    float s = red[0];
    for (int i = 1; i < nwaves; i++) s += red[i];
    red[31] = s;
  }
  __syncthreads();
  return red[31];
}

// packed 2-value block reduce (one barrier sequence); per-component order identical
// to two sequential blockReduceSumF calls -> bit-exact. red >= 32 floats; nwaves <= 8.
__device__ __forceinline__ float2 blockReduceSum2F(float a, float b, float* red, int tid, int nwaves) {
  #pragma unroll
  for (int off = 32; off > 0; off >>= 1) { a += __shfl_xor(a, off); b += __shfl_xor(b, off); }
  __syncthreads();
  if ((tid & 63) == 0) { red[tid >> 6] = a; red[(tid >> 6) + 16] = b; }
  __syncthreads();
  if (tid == 0) {
    float sa = red[0], sb = red[16];
    for (int i = 1; i < nwaves; i++) { sa += red[i]; sb += red[16 + i]; }
    red[30] = sa; red[31] = sb;
  }
  __syncthreads();
  return make_float2(red[30], red[31]);
}

// 4-wave (256-thread) group reduce; seg = 4-float LDS segment for this group.
__device__ __forceinline__ float groupReduce4w(float v, float* seg, int tj) {
  #pragma unroll
  for (int off = 32; off > 0; off >>= 1) v += __shfl_xor(v, off);
  __syncthreads();
  if ((tj & 63) == 0) seg[tj >> 6] = v;
  __syncthreads();
  return (seg[0] + seg[1]) + (seg[2] + seg[3]);
}

// R18: bit-exact emulation of the old 256-thread blockReduceSumF, run on 64 threads.
// Thread t holds partials a0..a3 of conceptual lanes 4t+q (old tid = c2*4+q, c2=t).
// Old 64-lane butterfly offsets 32,16,8,4 map to real shfl_xor 8,4,2,1 (q bits are the
// low 2 lane bits); old offsets 2,1 become in-thread adds (FP add is bitwise
// commutative, so pair order matches); cross-wave sum stays sequential red[0..3].
__device__ __forceinline__ float emulReduce256(float a0, float a1, float a2, float a3) {
  #pragma unroll
  for (int off = 8; off >= 1; off >>= 1) {
    a0 += __shfl_xor(a0, off);
    a1 += __shfl_xor(a1, off);
    a2 += __shfl_xor(a2, off);
    a3 += __shfl_xor(a3, off);
  }
  float b0 = a0 + a2;   // old offset 2
  float b1 = a1 + a3;
  float w  = b0 + b1;   // old offset 1
  float r0 = __shfl(w, 0), r1 = __shfl(w, 16), r2 = __shfl(w, 32), r3 = __shfl(w, 48);
  return ((r0 + r1) + r2) + r3;
}

// ---------------- K0a: pack conv2 weights -> w2t2[cc][c2][28] (229 KB) ----------------
__global__ void k0_w2t(const float* __restrict__ w2, float* __restrict__ w2t2) {
  int i = blockIdx.x * 256 + threadIdx.x;  // over 57344
  if (i >= 57344) return;
  int cc = i / 1792;
  int r = i - cc * 1792;
  int c2 = r / 28;
  int k = r - c2 * 28;
  w2t2[i] = (k < 25) ? w2[c2 * 800 + cc * 25 + k] : 0.0f;
}

// ---------------- K1: conv1 + ternarize -> sign map + alpha1 (f32) ----------------
// (512,4): VGPR cap 128, 2 blocks/CU — no spill (R16 fix, confirmed R2).
__global__ __launch_bounds__(512, 4) void k1_conv1(
    const float* __restrict__ x, const float* __restrict__ w1, const float* __restrict__ b1,
    signed char* __restrict__ s1full, float* __restrict__ alpha1) {
  __shared__ float xs[784];
  __shared__ float wsm[800];
  __shared__ float red[32];

  const int tid = threadIdx.x;
  const int smp = blockIdx.x;

  for (int j = tid; j < 784; j += 512) xs[j] = x[smp * 784 + j];
  for (int j = tid; j < 800; j += 512) wsm[j] = w1[j];
  __syncthreads();

  const int c = tid >> 4;
  const int g = tid & 15;
  const float bias = b1[c];
  const float* wc = &wsm[c * 25];

  float a[36];
  float asum = 0.0f;
  #pragma unroll
  for (int tt = 0; tt < 3; tt++) {
    const int t = g + (tt << 4);
    const int r = t >> 1;
    const int hx = (t & 1) * 12;
    float acc[12];
    #pragma unroll
    for (int i = 0; i < 12; i++) acc[i] = bias;
    #pragma unroll
    for (int ky = 0; ky < 5; ky++) {
      const float* xp = &xs[(r + ky) * 28 + hx];
      float xrow[16];
      *(float4*)&xrow[0]  = *(const float4*)&xp[0];
      *(float4*)&xrow[4]  = *(const float4*)&xp[4];
      *(float4*)&xrow[8]  = *(const float4*)&xp[8];
      *(float4*)&xrow[12] = *(const float4*)&xp[12];
      #pragma unroll
      for (int kx = 0; kx < 5; kx++) {
        const float w = wc[ky * 5 + kx];
        #pragma unroll
        for (int i = 0; i < 12; i++) acc[i] = fmaf(xrow[i + kx], w, acc[i]);
      }
    }
    #pragma unroll
    for (int i = 0; i < 12; i++) { a[tt * 12 + i] = acc[i]; asum += fabsf(acc[i]); }
  }

  float tot = blockReduceSumF(asum, red, tid, 8);
  float delta = (0.7f * tot) / 18432.0f;

  float msum = 0.0f, mcnt = 0.0f;
  #pragma unroll
  for (int i = 0; i < 36; i++) {
    float fa = fabsf(a[i]);
    if (fa > delta) { msum += fa; mcnt += 1.0f; }
  }
  float2 mm = blockReduceSum2F(msum, mcnt, red, tid, 8);
  if (tid == 0) alpha1[smp] = (mm.y > 0.0f) ? (mm.x / mm.y) : 0.0f;

  // packed sign stores: 12 bytes -> 3 dwords per tt.
  signed char* sp = s1full + (size_t)smp * 18432 + c * 576 + g * 12;
  #pragma unroll
  for (int tt = 0; tt < 3; tt++) {
    int s_[12];
    #pragma unroll
    for (int i = 0; i < 12; i++) {
      float v = a[tt * 12 + i];
      s_[i] = (v > delta) ? 1 : ((v < -delta) ? -1 : 0);
    }
    unsigned u0 = (s_[0] & 0xFF) | ((s_[1] & 0xFF) << 8) | ((s_[2] & 0xFF) << 16) |
                  (((unsigned)(s_[3] & 0xFF)) << 24);
    unsigned u1 = (s_[4] & 0xFF) | ((s_[5] & 0xFF) << 8) | ((s_[6] & 0xFF) << 16) |
                  (((unsigned)(s_[7] & 0xFF)) << 24);
    unsigned u2 = (s_[8] & 0xFF) | ((s_[9] & 0xFF) << 8) | ((s_[10] & 0xFF) << 16) |
                  (((unsigned)(s_[11] & 0xFF)) << 24);
    unsigned* wq = (unsigned*)(sp + tt * 192);
    wq[0] = u0; wq[1] = u1; wq[2] = u2;
  }
}

// ---------------- K2: BN1+maxpool+relu, conv2, ternarize ----
// R18: one thread per output channel (64 threads = 1 wave/block), full 8x8 plane in
// 64 accumulators. Per cc: 12 row reads (576 B LDS, broadcast across lanes) per 1600
// FMAs = 0.36 B/FMA (was 0.72) -> LDS pipe drops from 72% to ~36% of FMA demand.
// Weights amortize 4x. 8 blocks/CU (LDS-capped) = 2 waves/SIMD. Per-acc FMA chain
// order (cc, ky asc via t-streaming, kx asc) and all reduction trees bit-identical
// to the 256-thread version (see emulReduce256).
__global__ __launch_bounds__(64, 2) void k2_conv2(
    const signed char* __restrict__ s1full, const float* __restrict__ alpha1,
    const float* __restrict__ w2t2, const float* __restrict__ b2,
    const float* __restrict__ g1, const float* __restrict__ bt1,
    signed char* __restrict__ s2full, float* __restrict__ alpha2) {
  __shared__ float pooled[4608];
  __shared__ float g1l[32], bt1l[32];

  const int tid = threadIdx.x;
  const int smp = blockIdx.x;
  const float BNINV = (float)(1.0 / sqrt(1.0 + 1e-5));

  if (tid < 32) { g1l[tid] = g1[tid] * BNINV; bt1l[tid] = bt1[tid]; }
  __syncthreads();

  const float a1 = alpha1[smp];
  {
    const int ci = tid >> 1;        // channel 0..31
    const int h  = tid & 1;         // rows 6h..6h+5 of the 12 pooled rows
    const signed char* sbase = s1full + (size_t)smp * 18432 + ci * 576;
    float* pout = &pooled[ci * 144];
    const float gg = g1l[ci], bb = bt1l[ci];
    #pragma unroll
    for (int rr = 0; rr < 6; rr++) {
      const int py = h * 6 + rr;
      #pragma unroll
      for (int px = 0; px < 12; px++) {
        const signed char* sp = sbase + py * 48 + px * 2;
        char2 t0 = *(const char2*)sp;
        char2 t1 = *(const char2*)(sp + 24);
        float m = -1e30f;
        { float v = ((float)t0.x * a1) * gg + bb; m = (v > m) ? v : m; }
        { float v = ((float)t0.y * a1) * gg + bb; m = (v > m) ? v : m; }
        { float v = ((float)t1.x * a1) * gg + bb; m = (v > m) ? v : m; }
        { float v = ((float)t1.y * a1) * gg + bb; m = (v > m) ? v : m; }
        pout[py * 12 + px] = (m > 0.0f) ? m : 0.0f;
      }
    }
  }
  __syncthreads();

  const int c2 = tid;
  const float bias = b2[c2];
  float acc[8][8];
  #pragma unroll
  for (int r = 0; r < 8; r++)
    #pragma unroll
    for (int i = 0; i < 8; i++) acc[r][i] = bias;

  const float4* wp = ((const float4*)w2t2) + c2 * 7;  // 112 B/c2 -> 16B-aligned
  const float* pb = pooled;
  #pragma unroll 1
  for (int cc = 0; cc < 32; cc++) {
    const float4 W0 = wp[0], W1 = wp[1], W2 = wp[2], W3 = wp[3],
                 W4 = wp[4], W5 = wp[5], W6 = wp[6];
    const float wk[25] = {W0.x, W0.y, W0.z, W0.w, W1.x, W1.y, W1.z, W1.w,
                          W2.x, W2.y, W2.z, W2.w, W3.x, W3.y, W3.z, W3.w,
                          W4.x, W4.y, W4.z, W4.w, W5.x, W5.y, W5.z, W5.w, W6.x};
    #pragma unroll
    for (int t = 0; t < 12; t++) {
      float row[12];
      *(float4*)&row[0] = *(const float4*)&pb[t * 12];
      *(float4*)&row[4] = *(const float4*)&pb[t * 12 + 4];
      *(float4*)&row[8] = *(const float4*)&pb[t * 12 + 8];
      #pragma unroll
      for (int ky = 0; ky < 5; ky++) {
        const int r = t - ky;            // compile-time after unroll
        if (r >= 0 && r < 8) {
          #pragma unroll
          for (int kx = 0; kx < 5; kx++) {
            const float w = wk[ky * 5 + kx];
            #pragma unroll
            for (int i = 0; i < 8; i++) acc[r][i] = fmaf(row[i + kx], w, acc[r][i]);
          }
        }
      }
    }
    wp += 448;   // next cc slab (64 c2 * 7 float4)
    pb += 144;   // next channel plane
  }

  // partials of conceptual lanes 4t+q (q=0..3 <-> output rows 2q,2q+1), old order.
  float as0, as1, as2, as3;
  {
    float s[4];
    #pragma unroll
    for (int qq = 0; qq < 4; qq++) {
      float v = 0.0f;
      #pragma unroll
      for (int i = 0; i < 8; i++) v += fabsf(acc[2 * qq][i]) + fabsf(acc[2 * qq + 1][i]);
      s[qq] = v;
    }
    as0 = s[0]; as1 = s[1]; as2 = s[2]; as3 = s[3];
  }
  float tot = emulReduce256(as0, as1, as2, as3);
  float delta = (0.7f * tot) / 4096.0f;

  float ms[4], mc[4];
  #pragma unroll
  for (int qq = 0; qq < 4; qq++) {
    float msum = 0.0f, mcnt = 0.0f;
    #pragma unroll
    for (int i = 0; i < 8; i++) {
      float f0 = fabsf(acc[2 * qq][i]);
      if (f0 > delta) { msum += f0; mcnt += 1.0f; }
      float f1 = fabsf(acc[2 * qq + 1][i]);
      if (f1 > delta) { msum += f1; mcnt += 1.0f; }
    }
    ms[qq] = msum; mc[qq] = mcnt;
  }
  float msumT = emulReduce256(ms[0], ms[1], ms[2], ms[3]);
  float mcntT = emulReduce256(mc[0], mc[1], mc[2], mc[3]);
  if (tid == 0) alpha2[smp] = (mcntT > 0.0f) ? (msumT / mcntT) : 0.0f;

  // pack 64 sign bytes -> 4 uint4 stores (same addresses/bytes as old (c2,q) threads).
  signed char* so = s2full + (size_t)smp * 4096 + c2 * 64;
  #pragma unroll
  for (int pr = 0; pr < 4; pr++) {
    int t_[16];
    #pragma unroll
    for (int i = 0; i < 8; i++) {
      float v = acc[2 * pr][i];
      t_[i] = (v > delta) ? 1 : ((v < -delta) ? -1 : 0);
    }
    #pragma unroll
    for (int i = 0; i < 8; i++) {
      float v = acc[2 * pr + 1][i];
      t_[8 + i] = (v > delta) ? 1 : ((v < -delta) ? -1 : 0);
    }
    unsigned u0 = (t_[0] & 0xFF) | ((t_[1] & 0xFF) << 8) | ((t_[2] & 0xFF) << 16) |
                  (((unsigned)(t_[3] & 0xFF)) << 24);
    unsigned u1 = (t_[4] & 0xFF) | ((t_[5] & 0xFF) << 8) | ((t_[6] & 0xFF) << 16) |
                  (((unsigned)(t_[7] & 0xFF)) << 24);
    unsigned u2 = (t_[8] & 0xFF) | ((t_[9] & 0xFF) << 8) | ((t_[10] & 0xFF) << 16) |
                  (((unsigned)(t_[11] & 0xFF)) << 24);
    unsigned u3 = (t_[12] & 0xFF) | ((t_[13] & 0xFF) << 8) | ((t_[14] & 0xFF) << 16) |
                  (((unsigned)(t_[15] & 0xFF)) << 24);
    *(uint4*)(so + pr * 16) = make_uint4(u0, u1, u2, u3);
  }
}

// ---------------- K0t: transpose fc1 weights into w1t[k][o] (into dead s1full) ----------
__global__ void k0_transpose(const float* __restrict__ w1f, float* __restrict__ w1t) {
  int i = blockIdx.x * 256 + threadIdx.x;  // i over 524288
  int k = i >> 9;
  int o = i & 511;
  w1t[i] = w1f[o * 1024 + k];
}

// ---------------- K3: 4 samples/block; fc1 via transposed weights ----
__global__ __launch_bounds__(1024, 4) void k3_fc(
    const signed char* __restrict__ s2full, const float* __restrict__ alpha2,
    const float* __restrict__ w1t, const float* __restrict__ f1b,
    const float* __restrict__ w2f, const float* __restrict__ f2b,
    const float* __restrict__ g2, const float* __restrict__ bt2,
    float* __restrict__ out) {
  __shared__ float S[16384];
  __shared__ float fco[4][512];
  __shared__ float g2l[64], bt2l[64];
  __shared__ float redm[4][4];
  __shared__ float out2[4][10];

  const int tid = threadIdx.x;
  const int blk = blockIdx.x;
  const float BNINV = (float)(1.0 / sqrt(1.0 + 1e-5));

  if (tid < 64) { g2l[tid] = g2[tid] * BNINV; bt2l[tid] = bt2[tid]; }
  __syncthreads();

  float* h4 = S;
  for (int e = tid; e < 4096; e += 1024) {
    int j = e >> 2;
    int s = e & 3;
    int cc = j >> 4;
    int r = j & 15;
    int py = r >> 2;
    int px = r & 3;
    const signed char* sp = s2full + (size_t)(blk * 4 + s) * 4096 + cc * 64 + (py * 2) * 8 + px * 2;
    float a2 = alpha2[blk * 4 + s];
    float m = -1e30f;
    #pragma unroll
    for (int dy = 0; dy < 2; dy++)
      #pragma unroll
      for (int dx = 0; dx < 2; dx++) {
        float v = ((float)sp[dy * 8 + dx] * a2) * g2l[cc] + bt2l[cc];
        m = (v > m) ? v : m;
      }
    h4[j * 4 + s] = (m > 0.0f) ? m : 0.0f;
  }
  __syncthreads();

  const int kp = tid >> 7;
  const int og = tid & 127;
  float a00=0,a01=0,a02=0,a03=0, a10=0,a11=0,a12=0,a13=0;
  float a20=0,a21=0,a22=0,a23=0, a30=0,a31=0,a32=0,a33=0;
  const float4* w4 = (const float4*)w1t;
  const float4* h44 = (const float4*)h4;
  const int kbase = kp << 7;
  for (int kk = 0; kk < 128; kk++) {
    const int k = kbase + kk;
    const float4 wv = w4[(k << 7) + og];
    const float4 hv = h44[k];
    a00 = fmaf(hv.x, wv.x, a00); a01 = fmaf(hv.y, wv.x, a01);
    a02 = fmaf(hv.z, wv.x, a02); a03 = fmaf(hv.w, wv.x, a03);
    a10 = fmaf(hv.x, wv.y, a10); a11 = fmaf(hv.y, wv.y, a11);
    a12 = fmaf(hv.z, wv.y, a12); a13 = fmaf(hv.w, wv.y, a13);
    a20 = fmaf(hv.x, wv.z, a20); a21 = fmaf(hv.y, wv.z, a21);
    a22 = fmaf(hv.z, wv.z, a22); a23 = fmaf(hv.w, wv.z, a23);
    a30 = fmaf(hv.x, wv.w, a30); a31 = fmaf(hv.y, wv.w, a31);
    a32 = fmaf(hv.z, wv.w, a32); a33 = fmaf(hv.w, wv.w, a33);
  }
  __syncthreads();
  {
    float4* p4 = (float4*)S;
    const int base = (kp << 9) + (og << 2);
    p4[base + 0] = make_float4(a00, a01, a02, a03);
    p4[base + 1] = make_float4(a10, a11, a12, a13);
    p4[base + 2] = make_float4(a20, a21, a22, a23);
    p4[base + 3] = make_float4(a30, a31, a32, a33);
  }
  __syncthreads();

  for (int p = tid; p < 2048; p += 1024) {
    int o = p >> 2;
    int s = p & 3;
    float v = S[p];
    #pragma unroll
    for (int kp2 = 1; kp2 < 8; kp2++) v += S[kp2 * 2048 + p];
    fco[s][o] = v + f1b[o];
  }
  __syncthreads();

  float (*h3)[512] = (float(*)[512])S;
  const int sg = tid >> 8;
  const int tj = tid & 255;
  float v0 = fco[sg][tj];
  float v1 = fco[sg][tj + 256];
  float av0 = fabsf(v0), av1 = fabsf(v1);
  float tot = groupReduce4w(av0 + av1, redm[sg], tj);
  float delta = (0.7f * tot) / 512.0f;
  float m0 = (av0 > delta) ? av0 : 0.0f;
  float m1 = (av1 > delta) ? av1 : 0.0f;
  float msum = groupReduce4w(m0 + m1, redm[sg], tj);
  float mcnt = groupReduce4w(((av0 > delta) ? 1.0f : 0.0f) + ((av1 > delta) ? 1.0f : 0.0f),
                             redm[sg], tj);
  float alpha3 = (mcnt > 0.0f) ? (msum / mcnt) : 0.0f;
  {
    float t0 = (v0 > delta) ? 1.0f : ((v0 < -delta) ? -1.0f : 0.0f);
    float hv0 = t0 * alpha3;
    h3[sg][tj] = (hv0 > 0.0f) ? hv0 : 0.0f;
    float t1 = (v1 > delta) ? 1.0f : ((v1 < -delta) ? -1.0f : 0.0f);
    float hv1 = t1 * alpha3;
    h3[sg][tj + 256] = (hv1 > 0.0f) ? hv1 : 0.0f;
  }
  __syncthreads();

  const int lane = tid & 63;
  const int wid = tid >> 6;
  for (int t = wid; t < 40; t += 16) {
    int s = t / 10;
    int o = t - s * 10;
    float acc = 0.0f;
    #pragma unroll
    for (int m = 0; m < 8; m++) {
      int j = lane + (m << 6);
      acc = fmaf(h3[s][j], w2f[o * 512 + j], acc);
    }
    #pragma unroll
    for (int off = 32; off > 0; off >>= 1) acc += __shfl_xor(acc, off);
    if (lane == 0) out2[s][o] = acc + f2b[o];
  }
  __syncthreads();

  if (tid < 4) {
    int s = tid;
    float t2 = 0.0f;
    for (int i = 0; i < 10; i++) t2 += fabsf(out2[s][i]);
    float d = (0.7f * t2) / 10.0f;
    float ms = 0.0f, mc = 0.0f;
    for (int i = 0; i < 10; i++) {
      float a = fabsf(out2[s][i]);
      if (a > d) { ms += a; mc += 1.0f; }
    }
    float al = (mc > 0.0f) ? (ms / mc) : 0.0f;
    for (int i = 0; i < 10; i++) {
      float vv = out2[s][i];
      float sv = (vv > d) ? 1.0f : ((vv < -d) ? -1.0f : 0.0f);
      out[(size_t)(blk * 4 + s) * 10 + i] = sv * al;
    }
  }
}

// assumption-violation marker
__global__ void k_marker(float* __restrict__ out, int n, float val) {
  int i = blockIdx.x * 256 + threadIdx.x;
  if (i < n) out[i] = val;
}

extern "C" void kernel_launch(void* const* d_in, const int* in_sizes, int n_in,
                              void* d_out, int out_size, void* d_ws, size_t ws_size,
                              hipStream_t stream) {
  float* out = (float*)d_out;

  static const int expect[13] = {1605632, 800, 32, 32, 32, 51200, 64, 64, 64,
                                 524288, 512, 5120, 10};
  float marker = 0.0f;
  if (n_in != 13) marker = 304.0f;
  else {
    for (int i = 0; i < 13; i++)
      if (in_sizes[i] != expect[i]) { marker = 320.0f + 16.0f * i; break; }
  }
  if (marker == 0.0f && out_size != 20480) marker = 560.0f;

  float* alpha1 = (float*)d_ws;                           // 2048
  float* alpha2 = alpha1 + BATCH;                         // 2048
  float* w2t2   = alpha2 + BATCH;                         // 57344 (229 KB, padded)
  signed char* s1full = (signed char*)(w2t2 + 57344);     // 2048*18432 (dead after k2;
                                                          //  first 2MB reused as w1t)
  signed char* s2full = s1full + (size_t)BATCH * 18432;   // 2048*4096
  size_t needed = (size_t)((s2full + (size_t)BATCH * 4096) - (signed char*)d_ws);
  if (marker == 0.0f && ws_size < needed) marker = 576.0f;

  if (marker != 0.0f) {
    k_marker<<<dim3((out_size + 255) / 256), dim3(256), 0, stream>>>(out, out_size, marker);
    return;
  }

  const float* x   = (const float*)d_in[0];
  const float* c1w = (const float*)d_in[1];
  const float* c1b = (const float*)d_in[2];
  const float* g1  = (const float*)d_in[3];
  const float* bt1 = (const float*)d_in[4];
  const float* c2w = (const float*)d_in[5];
  const float* c2b = (const float*)d_in[6];
  const float* g2  = (const float*)d_in[7];
  const float* bt2 = (const float*)d_in[8];
  const float* f1w = (const float*)d_in[9];
  const float* f1b = (const float*)d_in[10];
  const float* f2w = (const float*)d_in[11];
  const float* f2b = (const float*)d_in[12];

  float* w1t = (float*)s1full;

  k0_w2t<<<dim3(224), dim3(256), 0, stream>>>(c2w, w2t2);
  k1_conv1<<<dim3(BATCH), dim3(512), 0, stream>>>(x, c1w, c1b, s1full, alpha1);
  k2_conv2<<<dim3(BATCH), dim3(64), 0, stream>>>(s1full, alpha1, w2t2, c2b, g1, bt1, s2full, alpha2);
  k0_transpose<<<dim3(2048), dim3(256), 0, stream>>>(f1w, w1t);
  k3_fc<<<dim3(BATCH / 4), dim3(1024), 0, stream>>>(s2full, alpha2, w1t, f1b, f2w, f2b, g2, bt2, out);
}